// Round 1
// 920.608 us; speedup vs baseline: 1.0452x; 1.0452x over previous
//
#include <hip/hip_runtime.h>

typedef unsigned short u16;
typedef unsigned int u32;
typedef __bf16 bf16x8 __attribute__((ext_vector_type(8)));
typedef float f32x4 __attribute__((ext_vector_type(4)));

#define NTOK 8192
#define CDIM 768
#define HDIM 3072
#define NEXP 8
#define NPAIR 16384

__device__ __forceinline__ float b2f(u16 u){ u32 v = ((u32)u)<<16; float f; __builtin_memcpy(&f,&v,4); return f; }
__device__ __forceinline__ u16 f2b(float f){ u32 u; __builtin_memcpy(&u,&f,4); u32 r = (u + 0x7FFF + ((u>>16)&1)) >> 16; return (u16)r; }
__device__ __forceinline__ int iclamp(int v,int lo,int hi){ return v<lo?lo:(v>hi?hi:v); }

// gelu via Abramowitz-Stegun 7.1.26 erf (|err| <= 1.5e-7 on erf, ~7e-7 abs on gelu —
// far below bf16 output rounding; replaces ~40-inst libm erff with ~14 VALU ops)
__device__ __forceinline__ float gelu_f(float v){
  float x = fabsf(v)*0.70710678118654752f;
  float t = __builtin_amdgcn_rcpf(1.0f + 0.3275911f*x);
  float p = ((((1.061405429f*t - 1.453152027f)*t + 1.421413741f)*t - 0.284496736f)*t + 0.254829592f)*t;
  float er = 1.0f - p*__expf(-x*x);
  er = copysignf(er, v);
  return 0.5f*v*(1.0f+er);
}

// async 16B global->LDS (m97 pattern): per-lane global addr OK; LDS dest = uniform base + lane*16
__device__ __forceinline__ void gl2l16(const void* g, void* l){
  __builtin_amdgcn_global_load_lds((const __attribute__((address_space(1))) void*)g,
                                   (__attribute__((address_space(3))) void*)l, 16, 0, 0);
}

// ---------------- dtype detect: fp32 viewed as u16 has garbage exponents ----------------
__global__ void detect_k(const u16* __restrict__ x, int* __restrict__ flagp){
  __shared__ int cnt;
  if (threadIdx.x==0) cnt=0;
  __syncthreads();
  int bad=0;
  for (int i=threadIdx.x; i<2048; i+=256){
    u16 u = x[i];
    int ex = (u>>7)&0xFF;
    if (ex >= 134) bad++;   // |v|>=128: never for N(0,1) bf16; ~47% of fp32 low halfwords
  }
  if (bad) atomicAdd(&cnt, bad);
  __syncthreads();
  if (threadIdx.x==0) *flagp = (cnt > 32) ? 1 : 0;   // 1 = inputs are fp32
}

// ---------------- convert (fp32->bf16) or copy (bf16), 4 elems/thread ----------------
__global__ __launch_bounds__(256) void conv_k(const void* __restrict__ src, u16* __restrict__ dst,
                                              int n4, const int* __restrict__ flagp){
  int i = blockIdx.x*256 + threadIdx.x;
  if (i >= n4) return;
  if (*flagp){
    float4 v = ((const float4*)src)[i];
    ushort4 o; o.x=f2b(v.x); o.y=f2b(v.y); o.z=f2b(v.z); o.w=f2b(v.w);
    ((ushort4*)dst)[i] = o;
  } else {
    ((ushort4*)dst)[i] = ((const ushort4*)src)[i];
  }
}

// ---------------- router: reads ORIGINAL inputs (fp32 or bf16), fp64 exact logits ----------------
__global__ __launch_bounds__(256) void router_k(const void* __restrict__ xraw, const void* __restrict__ Wrraw,
    const int* __restrict__ flagp,
    int* __restrict__ tok_e, float* __restrict__ tok_w, int* __restrict__ counts){
  int fp32f = *flagp;
  int tok = blockIdx.x*4 + (threadIdx.x>>6);
  int lane = threadIdx.x & 63;
  double acc[8];
  #pragma unroll
  for(int e=0;e<8;e++) acc[e]=0.0;
  for(int j=0;j<12;j++){
    int c = j*64 + lane;
    if (fp32f){
      double xv = (double)((const float*)xraw)[(size_t)tok*CDIM + c];
      const float* wr = (const float*)Wrraw + (size_t)c*8;
      float4 w0 = *(const float4*)wr;
      float4 w1 = *(const float4*)(wr+4);
      acc[0] += xv*(double)w0.x; acc[1] += xv*(double)w0.y;
      acc[2] += xv*(double)w0.z; acc[3] += xv*(double)w0.w;
      acc[4] += xv*(double)w1.x; acc[5] += xv*(double)w1.y;
      acc[6] += xv*(double)w1.z; acc[7] += xv*(double)w1.w;
    } else {
      double xv = (double)b2f(((const u16*)xraw)[(size_t)tok*CDIM + c]);
      uint4 wv = *(const uint4*)((const u16*)Wrraw + (size_t)c*8);
      acc[0] += xv*(double)b2f((u16)(wv.x&0xFFFF));
      acc[1] += xv*(double)b2f((u16)(wv.x>>16));
      acc[2] += xv*(double)b2f((u16)(wv.y&0xFFFF));
      acc[3] += xv*(double)b2f((u16)(wv.y>>16));
      acc[4] += xv*(double)b2f((u16)(wv.z&0xFFFF));
      acc[5] += xv*(double)b2f((u16)(wv.z>>16));
      acc[6] += xv*(double)b2f((u16)(wv.w&0xFFFF));
      acc[7] += xv*(double)b2f((u16)(wv.w>>16));
    }
  }
  #pragma unroll
  for(int e=0;e<8;e++){
    #pragma unroll
    for(int off=32;off>0;off>>=1) acc[e] += __shfl_down(acc[e], off);
  }
  if (lane==0){
    int i0=0; double b0=acc[0];
    #pragma unroll
    for(int e=1;e<8;e++) if(acc[e]>b0){ b0=acc[e]; i0=e; }
    int i1=(i0+1)&7; double b1v=-1e300;
    #pragma unroll
    for(int e=0;e<8;e++) if(e!=i0 && acc[e]>b1v){ b1v=acc[e]; i1=e; }
    double Z = 0.0;
    #pragma unroll
    for(int e=0;e<8;e++) Z += exp(acc[e]-b0);
    double pr0 = 1.0/Z;
    double pr1 = exp(b1v-b0)/Z;
    double s = pr0+pr1+1e-9;
    tok_e[2*tok]=i0; tok_e[2*tok+1]=i1;
    tok_w[2*tok]=(float)(pr0/s); tok_w[2*tok+1]=(float)(pr1/s);
    atomicAdd(&counts[i0],1); atomicAdd(&counts[i1],1);
  }
}

// ---------------- counts -> offsets/cursors + utilization output ----------------
__global__ void offsets_k(const int* __restrict__ counts, int* __restrict__ offsets,
                          int* __restrict__ cursor, void* __restrict__ dout,
                          const int* __restrict__ flagp){
  if (threadIdx.x==0 && blockIdx.x==0){
    int fp32f = *flagp;
    int s=0, tot=0;
    for(int e=0;e<8;e++) tot += counts[e];
    for(int e=0;e<8;e++){ offsets[e]=s; cursor[e]=s; s+=counts[e]; }
    offsets[8]=s;
    float inv = 1.f/((float)tot + 1e-9f);
    for(int e=0;e<8;e++){
      float val = (float)counts[e]*inv;
      if (fp32f) ((float*)dout)[(size_t)NTOK*CDIM + e] = val;
      else       ((u16*)dout)[(size_t)NTOK*CDIM + e]   = f2b(val);
    }
  }
}

// ---------------- scatter tokens into per-expert segments (fully clamped) ----------------
__global__ __launch_bounds__(256) void scatter_k(const int* __restrict__ tok_e, int* __restrict__ cursor,
    int* __restrict__ pair_tok, int* __restrict__ tok_pos){
  int tkn = blockIdx.x*256 + threadIdx.x;
  if (tkn >= NTOK) return;
  #pragma unroll
  for(int j=0;j<2;j++){
    int e = tok_e[2*tkn+j] & 7;
    int p = atomicAdd(&cursor[e], 1);
    p = iclamp(p, 0, NPAIR-1);
    pair_tok[p] = tkn;
    tok_pos[2*tkn+j] = p;
  }
}

// ---------------- transpose per expert, fused dtype conversion: in[R][Cc] -> out[Cc][R] bf16 ----------------
__global__ __launch_bounds__(256) void transpose_k(const void* __restrict__ inv, u16* __restrict__ out,
                                                   int R, int Cc, const int* __restrict__ flagp){
  __shared__ u16 T[64][65];
  int fp32f = *flagp;
  int ex = blockIdx.z;
  size_t base = (size_t)ex*R*Cc;
  out += base;
  int c0 = blockIdx.x*64, r0 = blockIdx.y*64;
  int tx = threadIdx.x & 31, ty = threadIdx.x >> 5;
  #pragma unroll
  for(int i=0;i<8;i++){
    int row = ty + i*8;
    size_t idx = base + (size_t)(r0+row)*Cc + c0 + tx*2;
    u32 v;
    if (fp32f){
      float2 f2v = *(const float2*)((const float*)inv + idx);
      v = (u32)f2b(f2v.x) | ((u32)f2b(f2v.y)<<16);
    } else {
      v = *(const u32*)((const u16*)inv + idx);
    }
    T[row][tx*2]   = (u16)(v&0xFFFF);
    T[row][tx*2+1] = (u16)(v>>16);
  }
  __syncthreads();
  #pragma unroll
  for(int i=0;i<8;i++){
    int row = ty + i*8;
    u32 lo = T[tx*2][row], hi = T[tx*2+1][row];
    *(u32*)(out + (size_t)(c0+row)*R + r0 + tx*2) = lo | (hi<<16);
  }
}

// ---------------- grouped GEMM: 128x128 tile, BK=64, 2-phase double-buffered pipeline ----------------
// T3-minimum recipe (m230/m248, 622 TF @128x128): issue next K-tile's global_load_lds BEFORE
// computing the current tile; ONE vmcnt(0)-drain barrier per K-tile (__syncthreads). The loads
// for tile k+1 stay in flight underneath tile k's ds_read+MFMA.
// LDS: row-major [row][64 u16] = 128 B/row, linear (required by global_load_lds). 8-chunk XOR
// swizzle phys = logical ^ (row&7), applied by pre-swizzling the per-lane GLOBAL source address
// (rule 21: both-sides-or-neither). ds_read_b128: 16 lanes spread over all 8 chunks = 32 banks,
// 2 lanes/16B-span = free (m136).
// EPI 0: gelu(acc + bias) -> bf16   EPI 1: acc + bias -> fp32
#define BM 128
#define BN 128
#define BK 64

template<int EPI>
__global__ __launch_bounds__(256) void gemm_k(
    const u16* __restrict__ Abase, const int* __restrict__ pair_tok, int astride,
    const u16* __restrict__ Bt, const u16* __restrict__ bias,
    const int* __restrict__ offsets, int K, int N,
    u16* __restrict__ out_bf, float* __restrict__ out_f)
{
  int e = blockIdx.z;
  int seg0 = iclamp(offsets[e],   0, NPAIR);
  int seg1 = iclamp(offsets[e+1], seg0, NPAIR);
  int Me = seg1 - seg0;
  int m0 = blockIdx.x * BM;
  if (m0 >= Me) return;
  int n0 = blockIdx.y * BN;

  alignas(16) __shared__ u16 As[2*BM*BK];   // 32 KB
  alignas(16) __shared__ u16 Bs[2*BN*BK];   // 32 KB

  int t = threadIdx.x;
  int wave = t>>6, lane = t&63;
  int wm = (wave>>1)*64, wn = (wave&1)*64;
  int lr = lane&15, quad = lane>>4;

  // staging: each wave stages 32 rows of A and 32 rows of B per K-tile, 4 issues each.
  // One issue = 64 lanes x 16B = 8 rows of 128B. lane: row = base + (lane>>3), phys chunk = lane&7.
  // Pre-swizzled logical source chunk cl = (lane&7) ^ (lane>>3)  (row&7 == lane>>3, rows 8-aligned).
  int srow = lane>>3;
  int cl   = (lane&7) ^ srow;
  const u16* aptr[4]; const u16* bptr[4];
  int lbase[4];
  const u16* bbase = Bt + (size_t)e*(size_t)N*K;
  #pragma unroll
  for(int i=0;i<4;i++){
    int tr = wave*32 + i*8 + srow;                 // tile-local row 0..127
    int rr = iclamp(seg0 + m0 + tr, 0, seg1-1);
    int row = pair_tok ? iclamp(pair_tok[rr], 0, NTOK-1) : rr;
    aptr[i] = Abase + (size_t)row*astride + cl*8;
    bptr[i] = bbase + (size_t)(n0+tr)*K + cl*8;
    lbase[i] = (wave*32 + i*8)*BK;                 // wave-uniform LDS base (u16 units)
  }

  f32x4 acc[4][4];
  #pragma unroll
  for(int i=0;i<4;i++)
    #pragma unroll
    for(int j=0;j<4;j++) acc[i][j]=(f32x4){0.f,0.f,0.f,0.f};

  // prologue: stage K-tile 0 into buffer 0
  #pragma unroll
  for(int i=0;i<4;i++){ gl2l16(aptr[i], &As[lbase[i]]); gl2l16(bptr[i], &Bs[lbase[i]]); }
  __syncthreads();   // vmcnt(0) drain + barrier: tile 0 resident

  int nt = K/BK;
  int cb = 0;                                      // current buffer offset (0 or BM*BK)
  for(int kt=0; kt<nt; ++kt){
    // issue next tile's loads FIRST — they fly under this tile's compute
    if (kt+1 < nt){
      int k0 = (kt+1)*BK;
      int nb = cb ^ (BM*BK);
      #pragma unroll
      for(int i=0;i<4;i++){ gl2l16(aptr[i]+k0, &As[nb+lbase[i]]); gl2l16(bptr[i]+k0, &Bs[nb+lbase[i]]); }
    }
    // ds_read fragments from current buffer (compiler emits fine-grained lgkmcnt before MFMA)
    bf16x8 af[4][2], bfr[4][2];
    #pragma unroll
    for(int i=0;i<4;i++){
      int ra = wm+i*16+lr;
      int rb = wn+i*16+lr;
      #pragma unroll
      for(int ks=0;ks<2;ks++){
        af[i][ks]  = *(const bf16x8*)(&As[cb + ra*BK + ((ks*4+quad) ^ (ra&7))*8]);
        bfr[i][ks] = *(const bf16x8*)(&Bs[cb + rb*BK + ((ks*4+quad) ^ (rb&7))*8]);
      }
    }
    #pragma unroll
    for(int ks=0;ks<2;ks++)
      #pragma unroll
      for(int i=0;i<4;i++)
        #pragma unroll
        for(int j=0;j<4;j++)
          acc[i][j] = __builtin_amdgcn_mfma_f32_16x16x32_bf16(af[i][ks], bfr[j][ks], acc[i][j], 0,0,0);
    __syncthreads();   // vmcnt(0): next tile landed; also fences buffer reuse
    cb ^= (BM*BK);
  }

  // epilogue: D layout col=lane&15, row=quad*4+reg  [verified m89/m91]
  #pragma unroll
  for(int i=0;i<4;i++){
    int mm_base = wm + i*16 + quad*4;
    #pragma unroll
    for(int j=0;j<4;j++){
      int nn = n0 + wn + j*16 + lr;
      float bv = b2f(bias[(size_t)e*N + nn]);
      #pragma unroll
      for(int rg=0;rg<4;rg++){
        int mm = m0 + mm_base + rg;
        if (mm < Me){
          int r = seg0 + mm;
          float v = acc[i][j][rg] + bv;
          if (EPI==0) out_bf[(size_t)r*N + nn] = f2b(gelu_f(v));
          else        out_f[(size_t)r*N + nn] = v;
        }
      }
    }
  }
}

// ---------------- combine: out[tok] = w0*y[pos0] + w1*y[pos1] ----------------
__global__ __launch_bounds__(192) void combine_k(const float* __restrict__ y,
    const int* __restrict__ tok_pos, const float* __restrict__ tok_w,
    void* __restrict__ outv, const int* __restrict__ flagp){
  int fp32f = *flagp;
  int tkn = blockIdx.x;
  int c = threadIdx.x*4;
  int p0 = iclamp(tok_pos[2*tkn],   0, NPAIR-1);
  int p1 = iclamp(tok_pos[2*tkn+1], 0, NPAIR-1);
  float w0 = tok_w[2*tkn], w1 = tok_w[2*tkn+1];
  float4 a = *(const float4*)(y + (size_t)p0*CDIM + c);
  float4 b = *(const float4*)(y + (size_t)p1*CDIM + c);
  float4 o4;
  o4.x = w0*a.x + w1*b.x;
  o4.y = w0*a.y + w1*b.y;
  o4.z = w0*a.z + w1*b.z;
  o4.w = w0*a.w + w1*b.w;
  if (fp32f){
    *(float4*)((float*)outv + (size_t)tkn*CDIM + c) = o4;
  } else {
    ushort4 o;
    o.x = f2b(o4.x); o.y = f2b(o4.y); o.z = f2b(o4.z); o.w = f2b(o4.w);
    *(ushort4*)((u16*)outv + (size_t)tkn*CDIM + c) = o;
  }
}

extern "C" void kernel_launch(void* const* d_in, const int* in_sizes, int n_in,
                              void* d_out, int out_size, void* d_ws, size_t ws_size,
                              hipStream_t stream) {
  const void* x  = d_in[0];
  const void* Wr = d_in[1];
  const void* W1 = d_in[2];
  const void* b1 = d_in[3];
  const void* W2 = d_in[4];
  const void* b2 = d_in[5];

  // ws carve (all offsets multiple of 16)
  char* w = (char*)d_ws;
  int*   flagp    = (int*)w;                   // 1
  int*   counts   = (int*)(w + 256);           // 8
  int*   offsets  = (int*)(w + 512);           // 9
  int*   cursor   = (int*)(w + 768);           // 8
  int*   tok_e    = (int*)(w + 1024);          // 16384
  float* tok_w    = (float*)(w + 66560);       // 16384
  int*   tok_pos  = (int*)(w + 132096);        // 16384
  int*   pair_tok = (int*)(w + 197632);        // 16384
  u16*   b1c      = (u16*)(w + 263168);        // 24576 B
  u16*   b2c      = (u16*)(w + 312320);        // 6144 B
  u16*   xc       = (u16*)(w + 336896);        // 12582912 B
  u16*   W1t      = (u16*)(w + 12919808);      // [E][H][C] 37748736 B
  u16*   W2t      = W1t + (size_t)NEXP*CDIM*HDIM;      // [E][C][H] 37748736 B
  u16*   h        = W2t + (size_t)NEXP*CDIM*HDIM;      // [NPAIR][H] bf16
  float* y        = (float*)(h + (size_t)NPAIR*HDIM);  // [NPAIR][C] fp32
  size_t need = 189080576ull + (size_t)NPAIR*CDIM*4;   // ~239.4 MB
  if (ws_size < need) { // diagnosable fallback: clean absmax=ref-absmax failure, no fault
    hipMemsetAsync(d_out, 0, (size_t)out_size*2, stream);
    return;
  }

  hipMemsetAsync(counts, 0, 32, stream);
  detect_k<<<1, 256, 0, stream>>>((const u16*)x, flagp);
  conv_k<<<6144, 256, 0, stream>>>(x,  xc,  NTOK*CDIM/4, flagp);
  conv_k<<<24,   256, 0, stream>>>(b1, b1c, NEXP*HDIM/4, flagp);
  conv_k<<<6,    256, 0, stream>>>(b2, b2c, NEXP*CDIM/4, flagp);
  // W1 [E][C][H] -> W1t [E][H][C]; W2 [E][H][C] -> W2t [E][C][H]
  transpose_k<<<dim3(HDIM/64, CDIM/64, NEXP), 256, 0, stream>>>(W1, W1t, CDIM, HDIM, flagp);
  transpose_k<<<dim3(CDIM/64, HDIM/64, NEXP), 256, 0, stream>>>(W2, W2t, HDIM, CDIM, flagp);
  // router reads ORIGINAL (un-quantized) inputs
  router_k<<<NTOK/4, 256, 0, stream>>>(x, Wr, flagp, tok_e, tok_w, counts);
  offsets_k<<<1, 64, 0, stream>>>(counts, offsets, cursor, d_out, flagp);
  scatter_k<<<NTOK/256, 256, 0, stream>>>(tok_e, cursor, pair_tok, tok_pos);
  // GEMM1: h = gelu(x_gathered @ W1[e] + b1[e])   [Me x 3072] bf16
  gemm_k<0><<<dim3(NTOK/BM, HDIM/BN, NEXP), 256, 0, stream>>>(
      xc, pair_tok, CDIM, W1t, b1c, offsets, CDIM, HDIM, h, nullptr);
  // GEMM2: y = h @ W2[e] + b2[e]                  [Me x 768] fp32
  gemm_k<1><<<dim3(NTOK/BM, CDIM/BN, NEXP), 256, 0, stream>>>(
      h, nullptr, HDIM, W2t, b2c, offsets, HDIM, CDIM, nullptr, y);
  combine_k<<<NTOK, 192, 0, stream>>>(y, tok_pos, tok_w, d_out, flagp);
}